// Round 1
// baseline (1430.962 us; speedup 1.0000x reference)
//
#include <hip/hip_runtime.h>
#include <hip/hip_bf16.h>
#include <math.h>

// ---------------------------------------------------------------------------
// Problem: edge_embed = mlp2(pred_codes, We1,be1, We2,be2)   (relu on hidden)
//          type_pred  = mlp2(edge_embed, Wt1,bt1, Wt2,bt2)
//          type_output = softmax(type_pred, axis=1)
//          types_w = stack([1-p0, p1, p2, p3], axis=0)        (4, M)
//          multiW  = gate(types_w)
// Outputs concat: types_w (4M) | multiW (4M) | type_output (M*4) | edge_embed (M*512)
// M = 89700, d = 512, hidden2 = 128.
// obj_codes (d_in[0]) is UNUSED by the reference.
// ---------------------------------------------------------------------------

#define ALP 2.2f
#define BEL 0.025f
// 1/2.2 + 0.025 computed in double then truncated, matching python float64 constant
#define GATE_HI 0.4795454545454546f

// ---------------- fp32 tiled GEMM: C = act(A @ B + bias) -------------------
// A: M x K row-major, B: K x N row-major, C: M x N row-major.
// BM=BN=128, BK=8, 256 threads (16x16), 8x8 microtile per thread.
// N and K must be multiples of 128 / 8 (true for all our calls). M is guarded.
#define BM 128
#define BN 128
#define BK 8

template <bool RELU>
__global__ __launch_bounds__(256) void gemm_bias(
    const float* __restrict__ A, const float* __restrict__ B,
    const float* __restrict__ bias, float* __restrict__ C,
    int M, int N, int K)
{
    // +4 pad: keeps 16B alignment of each row while breaking bank-conflict strides
    __shared__ float As[BK][BM + 4];   // transposed: As[k][m]
    __shared__ float Bs[BK][BN + 4];   // Bs[k][n]

    const int tid = threadIdx.x;
    const int tx  = tid & 15;   // col group 0..15
    const int ty  = tid >> 4;   // row group 0..15
    const int m0  = blockIdx.x * BM;
    const int n0  = blockIdx.y * BN;

    // global staging assignments
    const int arow = tid >> 1;        // 0..127
    const int acg  = tid & 1;         // 0..1   (8 cols = 2 float4)
    const int brow = tid >> 5;        // 0..7
    const int bcg  = tid & 31;        // 0..31  (128 cols = 32 float4)
    const bool avalid = (m0 + arow) < M;

    const float* Aptr = A + (size_t)(m0 + arow) * K + acg * 4;
    const float* Bptr = B + (size_t)brow * N + n0 + bcg * 4;

    float acc[8][8];
#pragma unroll
    for (int i = 0; i < 8; ++i)
#pragma unroll
        for (int j = 0; j < 8; ++j) acc[i][j] = 0.0f;

    for (int k0 = 0; k0 < K; k0 += BK) {
        float4 av = make_float4(0.f, 0.f, 0.f, 0.f);
        if (avalid) av = *(const float4*)(Aptr + k0);
        float4 bv = *(const float4*)(Bptr + (size_t)k0 * N);

        __syncthreads();   // previous iteration's LDS reads complete
        As[acg * 4 + 0][arow] = av.x;
        As[acg * 4 + 1][arow] = av.y;
        As[acg * 4 + 2][arow] = av.z;
        As[acg * 4 + 3][arow] = av.w;
        *(float4*)&Bs[brow][bcg * 4] = bv;
        __syncthreads();

#pragma unroll
        for (int kk = 0; kk < BK; ++kk) {
            float a[8], b[8];
            *(float4*)&a[0] = *(const float4*)&As[kk][ty * 8];
            *(float4*)&a[4] = *(const float4*)&As[kk][ty * 8 + 4];
            *(float4*)&b[0] = *(const float4*)&Bs[kk][tx * 8];
            *(float4*)&b[4] = *(const float4*)&Bs[kk][tx * 8 + 4];
#pragma unroll
            for (int i = 0; i < 8; ++i)
#pragma unroll
                for (int j = 0; j < 8; ++j)
                    acc[i][j] = fmaf(a[i], b[j], acc[i][j]);
        }
    }

    // epilogue: bias (+relu), guarded store
    float bb[8];
#pragma unroll
    for (int j = 0; j < 8; ++j) bb[j] = bias[n0 + tx * 8 + j];

#pragma unroll
    for (int i = 0; i < 8; ++i) {
        int r = m0 + ty * 8 + i;
        if (r < M) {
            float4 v0, v1;
            float o[8];
#pragma unroll
            for (int j = 0; j < 8; ++j) {
                float v = acc[i][j] + bb[j];
                if (RELU) v = fmaxf(v, 0.0f);
                o[j] = v;
            }
            v0 = make_float4(o[0], o[1], o[2], o[3]);
            v1 = make_float4(o[4], o[5], o[6], o[7]);
            float* cp = C + (size_t)r * N + n0 + tx * 8;
            *(float4*)cp       = v0;
            *(float4*)(cp + 4) = v1;
        }
    }
}

// ------------- head: T = T1 @ Wt2 + bt2, softmax, stack, gate --------------
// T1: M x 128 (relu'd hidden). 64 rows per block, 256 threads.
__device__ __forceinline__ float gate_fn(float p) {
    if (p <= BEL) return 0.0f;
    if (p >= GATE_HI) return 1.0f;
    return ALP * (p - BEL);
}

__global__ __launch_bounds__(256) void head_kernel(
    const float* __restrict__ T1, const float* __restrict__ Wt2,
    const float* __restrict__ bt2, float* __restrict__ out, int M)
{
    __shared__ float Ts[64][129];   // +1 pad: row stride 129 -> conflict-free column reads
    __shared__ float Ws[128][4];
    __shared__ float bs[4];
    __shared__ float sm[4][64];

    const int tid = threadIdx.x;
    const int r0  = blockIdx.x * 64;

    if (tid < 128) {
        float4 w = *(const float4*)&Wt2[tid * 4];
        Ws[tid][0] = w.x; Ws[tid][1] = w.y; Ws[tid][2] = w.z; Ws[tid][3] = w.w;
    }
    if (tid < 4) bs[tid] = bt2[tid];

    // stage 64x128 tile of T1, coalesced float4, zero-fill OOB rows
#pragma unroll
    for (int i = 0; i < 8; ++i) {
        int g    = i * 1024 + tid * 4;   // tile-relative float index
        int grow = g >> 7;
        int gk   = g & 127;
        float4 v = make_float4(0.f, 0.f, 0.f, 0.f);
        if (r0 + grow < M) v = *(const float4*)&T1[(size_t)(r0 + grow) * 128 + gk];
        Ts[grow][gk + 0] = v.x;
        Ts[grow][gk + 1] = v.y;
        Ts[grow][gk + 2] = v.z;
        Ts[grow][gk + 3] = v.w;
    }
    __syncthreads();

    // 4 logits per row; thread (row=tid&63, col=tid>>6)
    {
        const int row = tid & 63;
        const int col = tid >> 6;
        float d = bs[col];
#pragma unroll
        for (int k = 0; k < 128; ++k)
            d = fmaf(Ts[row][k], Ws[k][col], d);
        sm[col][row] = d;
    }
    __syncthreads();

    if (tid < 64) {
        int r = r0 + tid;
        if (r < M) {
            float v0 = sm[0][tid], v1 = sm[1][tid], v2 = sm[2][tid], v3 = sm[3][tid];
            float mx = fmaxf(fmaxf(v0, v1), fmaxf(v2, v3));
            float e0 = expf(v0 - mx), e1 = expf(v1 - mx), e2 = expf(v2 - mx), e3 = expf(v3 - mx);
            float inv = 1.0f / (e0 + e1 + e2 + e3);
            float p0 = e0 * inv, p1 = e1 * inv, p2 = e2 * inv, p3 = e3 * inv;

            float tw0 = 1.0f - p0;
            float* TW = out;                     // (4, M)
            float* MW = out + (size_t)4 * M;     // (4, M)
            float* TO = out + (size_t)8 * M;     // (M, 4)

            TW[0 * (size_t)M + r] = tw0;
            TW[1 * (size_t)M + r] = p1;
            TW[2 * (size_t)M + r] = p2;
            TW[3 * (size_t)M + r] = p3;

            MW[0 * (size_t)M + r] = gate_fn(tw0);
            MW[1 * (size_t)M + r] = gate_fn(p1);
            MW[2 * (size_t)M + r] = gate_fn(p2);
            MW[3 * (size_t)M + r] = gate_fn(p3);

            *(float4*)&TO[(size_t)r * 4] = make_float4(p0, p1, p2, p3);
        }
    }
}

// ---------------------------------------------------------------------------
extern "C" void kernel_launch(void* const* d_in, const int* in_sizes, int n_in,
                              void* d_out, int out_size, void* d_ws, size_t ws_size,
                              hipStream_t stream)
{
    // inputs: 0 obj_codes (unused), 1 pred_codes (M x 512), 2 We1 (512x512),
    // 3 be1, 4 We2, 5 be2, 6 Wt1 (512x128), 7 bt1, 8 Wt2 (128x4), 9 bt2
    const float* pred = (const float*)d_in[1];
    const float* We1  = (const float*)d_in[2];
    const float* be1  = (const float*)d_in[3];
    const float* We2  = (const float*)d_in[4];
    const float* be2  = (const float*)d_in[5];
    const float* Wt1  = (const float*)d_in[6];
    const float* bt1  = (const float*)d_in[7];
    const float* Wt2  = (const float*)d_in[8];
    const float* bt2  = (const float*)d_in[9];

    const int M = in_sizes[1] / 512;

    float* out = (float*)d_out;
    float* EE  = out + (size_t)12 * M;          // edge_embed region (M x 512)

    float* H  = (float*)d_ws;                   // M x 512 fp32 scratch
    float* T1 = H + (size_t)M * 512;            // M x 128 fp32 scratch

    const int mt = (M + BM - 1) / BM;           // 701 M-tiles
    dim3 blk(256);

    // GEMM1: H = relu(pred @ We1 + be1)        (M,512)x(512,512)
    gemm_bias<true ><<<dim3(mt, 4), blk, 0, stream>>>(pred, We1, be1, H,  M, 512, 512);
    // GEMM2: EE = H @ We2 + be2                (M,512)x(512,512)
    gemm_bias<false><<<dim3(mt, 4), blk, 0, stream>>>(H,    We2, be2, EE, M, 512, 512);
    // GEMM3: T1 = relu(EE @ Wt1 + bt1)         (M,512)x(512,128)
    gemm_bias<true ><<<dim3(mt, 1), blk, 0, stream>>>(EE,   Wt1, bt1, T1, M, 128, 512);
    // head: logits, softmax, stack, gate
    head_kernel<<<dim3((M + 63) / 64), blk, 0, stream>>>(T1, Wt2, bt2, out, M);
}

// Round 2
// 635.142 us; speedup vs baseline: 2.2530x; 2.2530x over previous
//
#include <hip/hip_runtime.h>
#include <hip/hip_bf16.h>
#include <math.h>

// ---------------------------------------------------------------------------
// edge_embed = (relu(pred@We1+be1))@We2+be2        M x 512
// type_pred  = (relu(edge_embed@Wt1+bt1))@Wt2+bt2  M x 4
// softmax -> types_w (4,M), multiW=gate(types_w) (4,M), type_output (M,4)
// out concat: types_w | multiW | type_output | edge_embed.  M=89700, d=512.
// Strategy: bf16 MFMA (16x16x32) for the 3 big GEMMs, m97 structure.
// ---------------------------------------------------------------------------

#define ALP 2.2f
#define BEL 0.025f
#define GATE_HI 0.4795454545454546f

typedef __attribute__((ext_vector_type(8))) short bf16x8;
typedef __attribute__((ext_vector_type(4))) float f32x4;

__device__ __forceinline__ unsigned short f2bf(float f) {
    unsigned int u = __float_as_uint(f);
    u = (u + 0x7FFF + ((u >> 16) & 1)) >> 16;   // round-to-nearest-even
    return (unsigned short)u;
}

__device__ __forceinline__ void async_copy16(const unsigned short* g, unsigned short* l) {
    __builtin_amdgcn_global_load_lds(
        (const __attribute__((address_space(1))) unsigned int*)(g),
        (__attribute__((address_space(3))) unsigned int*)(l),
        16, 0, 0);
}

// ------------------------- prep: fp32 -> bf16 ------------------------------
__global__ __launch_bounds__(256) void cvt_bf16(
    const float* __restrict__ in, unsigned short* __restrict__ out, int n8)
{
    int idx = blockIdx.x * 256 + threadIdx.x;
    int stride = gridDim.x * 256;
    for (int i = idx; i < n8; i += stride) {
        const float4* p = (const float4*)(in + (size_t)i * 8);
        float4 a = p[0], b = p[1];
        ushort4* q = (ushort4*)(out + (size_t)i * 8);
        q[0] = make_ushort4(f2bf(a.x), f2bf(a.y), f2bf(a.z), f2bf(a.w));
        q[1] = make_ushort4(f2bf(b.x), f2bf(b.y), f2bf(b.z), f2bf(b.w));
    }
}

// ---------------- prep: transpose K x N fp32 -> N x K bf16 -----------------
__global__ __launch_bounds__(256) void transpose_cvt(
    const float* __restrict__ W, unsigned short* __restrict__ Wt, int K, int N)
{
    __shared__ float t[32][33];
    const int bk = blockIdx.x * 32, bn = blockIdx.y * 32;
    const int tx = threadIdx.x & 31, ty = threadIdx.x >> 5;   // 32 x 8
#pragma unroll
    for (int i = 0; i < 32; i += 8)
        t[ty + i][tx] = W[(size_t)(bk + ty + i) * N + bn + tx];
    __syncthreads();
#pragma unroll
    for (int i = 0; i < 32; i += 8)
        Wt[(size_t)(bn + ty + i) * K + bk + tx] = f2bf(t[tx][ty + i]);
}

// --------------------- bf16 MFMA GEMM (m97 structure) ----------------------
// A: M x K bf16 row-major.  Bt: N x K bf16 row-major (pre-transposed).
// C = act(A @ Bt^T + bias).  128x128 tile, BK=32, 256 threads (4 waves),
// each wave = 4x4 tiles of 16x16x32 MFMA.  K % 32 == 0, N % 128 == 0.
template <bool RELU, bool WF32, bool WBF16>
__global__ __launch_bounds__(256) void gemm_mfma(
    const unsigned short* __restrict__ A, const unsigned short* __restrict__ Bt,
    const float* __restrict__ bias,
    float* __restrict__ Cf, unsigned short* __restrict__ Cb,
    int M, int N, int K)
{
    __shared__ unsigned short As[128 * 32];   // [row][k] row-major, 8 KB
    __shared__ unsigned short Bs[128 * 32];   // [n][k]   row-major, 8 KB

    const int tid  = threadIdx.x;
    const int lane = tid & 63;
    const int wave = tid >> 6;
    const int m0   = blockIdx.x * 128;
    const int n0   = blockIdx.y * 128;

    const int wm = (wave & 1) * 64;   // wave's 64x64 sub-tile
    const int wn = (wave >> 1) * 64;
    const int fm   = lane & 15;       // row within 16-tile
    const int quad = lane >> 4;       // k-chunk selector (0..3)

    f32x4 acc[4][4];
#pragma unroll
    for (int i = 0; i < 4; ++i)
#pragma unroll
        for (int j = 0; j < 4; ++j)
            acc[i][j] = (f32x4){0.f, 0.f, 0.f, 0.f};

    // staging: chunk c (0..511): row = c>>2, kchunk = c&3; LDS bytes = c*16.
    // Within a wave, LDS offsets are lane-consecutive x16B (global_load_lds req).
    const int c0row = tid >> 2, c0k = tid & 3;           // round 0: c = tid
    const int c1row = (256 + tid) >> 2, c1k = tid & 3;   // round 1: c = 256+tid

    int a0row = m0 + c0row; if (a0row >= M) a0row = M - 1;
    int a1row = m0 + c1row; if (a1row >= M) a1row = M - 1;
    const unsigned short* Ag0 = A  + (size_t)a0row * K + c0k * 8;
    const unsigned short* Ag1 = A  + (size_t)a1row * K + c1k * 8;
    const unsigned short* Bg0 = Bt + (size_t)(n0 + c0row) * K + c0k * 8;
    const unsigned short* Bg1 = Bt + (size_t)(n0 + c1row) * K + c1k * 8;
    unsigned short* Al0 = As + (size_t)tid * 8;
    unsigned short* Al1 = As + (size_t)(256 + tid) * 8;
    unsigned short* Bl0 = Bs + (size_t)tid * 8;
    unsigned short* Bl1 = Bs + (size_t)(256 + tid) * 8;

    for (int k0 = 0; k0 < K; k0 += 32) {
        __syncthreads();                     // previous compute done before overwrite
        async_copy16(Ag0 + k0, Al0);
        async_copy16(Ag1 + k0, Al1);
        async_copy16(Bg0 + k0, Bl0);
        async_copy16(Bg1 + k0, Bl1);
        __syncthreads();                     // compiler drains vmcnt before barrier

        bf16x8 af[4], bfr[4];
#pragma unroll
        for (int i = 0; i < 4; ++i)
            af[i] = *(const bf16x8*)&As[(wm + i * 16 + fm) * 32 + quad * 8];
#pragma unroll
        for (int j = 0; j < 4; ++j)
            bfr[j] = *(const bf16x8*)&Bs[(wn + j * 16 + fm) * 32 + quad * 8];
#pragma unroll
        for (int i = 0; i < 4; ++i)
#pragma unroll
            for (int j = 0; j < 4; ++j)
                acc[i][j] = __builtin_amdgcn_mfma_f32_16x16x32_bf16(
                    af[i], bfr[j], acc[i][j], 0, 0, 0);
    }

    // epilogue: C/D layout col = lane&15, row = (lane>>4)*4 + reg  [m89/m91]
    const int ecol  = lane & 15;
    const int erow4 = (lane >> 4) * 4;
#pragma unroll
    for (int j = 0; j < 4; ++j) {
        const int col = n0 + wn + j * 16 + ecol;
        const float bv = bias[col];
#pragma unroll
        for (int i = 0; i < 4; ++i) {
#pragma unroll
            for (int rr = 0; rr < 4; ++rr) {
                const int row = m0 + wm + i * 16 + erow4 + rr;
                if (row < M) {
                    float v = acc[i][j][rr] + bv;
                    if (RELU) v = fmaxf(v, 0.f);
                    if (WF32)  Cf[(size_t)row * N + col] = v;
                    if (WBF16) Cb[(size_t)row * N + col] = f2bf(v);
                }
            }
        }
    }
}

// ------------- head: T = T1 @ Wt2 + bt2, softmax, stack, gate --------------
__device__ __forceinline__ float gate_fn(float p) {
    if (p <= BEL) return 0.0f;
    if (p >= GATE_HI) return 1.0f;
    return ALP * (p - BEL);
}

__global__ __launch_bounds__(256) void head_kernel(
    const float* __restrict__ T1, const float* __restrict__ Wt2,
    const float* __restrict__ bt2, float* __restrict__ out, int M)
{
    __shared__ float Ts[64][129];
    __shared__ float Ws[128][4];
    __shared__ float bs[4];
    __shared__ float sm[4][64];

    const int tid = threadIdx.x;
    const int r0  = blockIdx.x * 64;

    if (tid < 128) {
        float4 w = *(const float4*)&Wt2[tid * 4];
        Ws[tid][0] = w.x; Ws[tid][1] = w.y; Ws[tid][2] = w.z; Ws[tid][3] = w.w;
    }
    if (tid < 4) bs[tid] = bt2[tid];

#pragma unroll
    for (int i = 0; i < 8; ++i) {
        int g = i * 1024 + tid * 4;
        int grow = g >> 7, gk = g & 127;
        float4 v = make_float4(0.f, 0.f, 0.f, 0.f);
        if (r0 + grow < M) v = *(const float4*)&T1[(size_t)(r0 + grow) * 128 + gk];
        Ts[grow][gk + 0] = v.x; Ts[grow][gk + 1] = v.y;
        Ts[grow][gk + 2] = v.z; Ts[grow][gk + 3] = v.w;
    }
    __syncthreads();

    {
        const int row = tid & 63, col = tid >> 6;
        float d = bs[col];
#pragma unroll
        for (int k = 0; k < 128; ++k)
            d = fmaf(Ts[row][k], Ws[k][col], d);
        sm[col][row] = d;
    }
    __syncthreads();

    if (tid < 64) {
        int r = r0 + tid;
        if (r < M) {
            float v0 = sm[0][tid], v1 = sm[1][tid], v2 = sm[2][tid], v3 = sm[3][tid];
            float mx = fmaxf(fmaxf(v0, v1), fmaxf(v2, v3));
            float e0 = expf(v0 - mx), e1 = expf(v1 - mx), e2 = expf(v2 - mx), e3 = expf(v3 - mx);
            float inv = 1.0f / (e0 + e1 + e2 + e3);
            float p0 = e0 * inv, p1 = e1 * inv, p2 = e2 * inv, p3 = e3 * inv;
            float tw0 = 1.0f - p0;

            float* TW = out;
            float* MW = out + (size_t)4 * M;
            float* TO = out + (size_t)8 * M;
            TW[0 * (size_t)M + r] = tw0;
            TW[1 * (size_t)M + r] = p1;
            TW[2 * (size_t)M + r] = p2;
            TW[3 * (size_t)M + r] = p3;
            MW[0 * (size_t)M + r] = gate_fn(tw0);
            MW[1 * (size_t)M + r] = gate_fn(p1);
            MW[2 * (size_t)M + r] = gate_fn(p2);
            MW[3 * (size_t)M + r] = gate_fn(p3);
            *(float4*)&TO[(size_t)r * 4] = make_float4(p0, p1, p2, p3);
        }
    }
}

// ---------------------------------------------------------------------------
extern "C" void kernel_launch(void* const* d_in, const int* in_sizes, int n_in,
                              void* d_out, int out_size, void* d_ws, size_t ws_size,
                              hipStream_t stream)
{
    const float* pred = (const float*)d_in[1];
    const float* We1  = (const float*)d_in[2];
    const float* be1  = (const float*)d_in[3];
    const float* We2  = (const float*)d_in[4];
    const float* be2  = (const float*)d_in[5];
    const float* Wt1  = (const float*)d_in[6];
    const float* bt1  = (const float*)d_in[7];
    const float* Wt2  = (const float*)d_in[8];
    const float* bt2  = (const float*)d_in[9];

    const int M = in_sizes[1] / 512;

    float* out = (float*)d_out;
    float* EE  = out + (size_t)12 * M;              // edge_embed (M x 512) fp32

    // workspace layout (bytes, all 16B-aligned):
    //   predb  : M*512 bf16  (aliased later by EEb — pred dead after GEMM1)
    //   Hb     : M*512 bf16
    //   T1     : M*128 fp32
    //   We1t / We2t / Wt1t : transposed bf16 weights
    unsigned short* predb = (unsigned short*)d_ws;
    unsigned short* EEb   = predb;                  // alias (sequential use)
    unsigned short* Hb    = predb + (size_t)M * 512;
    float*          T1    = (float*)(Hb + (size_t)M * 512);
    unsigned short* We1t  = (unsigned short*)(T1 + (size_t)M * 128);
    unsigned short* We2t  = We1t + 512 * 512;
    unsigned short* Wt1t  = We2t + 512 * 512;

    const int mt = (M + 127) / 128;                 // 701 M-tiles
    dim3 blk(256);

    // ---- prep ----
    cvt_bf16<<<dim3(1024), blk, 0, stream>>>(pred, predb, M * 512 / 8);
    transpose_cvt<<<dim3(16, 16), blk, 0, stream>>>(We1, We1t, 512, 512);
    transpose_cvt<<<dim3(16, 16), blk, 0, stream>>>(We2, We2t, 512, 512);
    transpose_cvt<<<dim3(16, 4),  blk, 0, stream>>>(Wt1, Wt1t, 512, 128);

    // ---- GEMM1: Hb = relu(pred @ We1 + be1), bf16 out ----
    gemm_mfma<true, false, true><<<dim3(mt, 4), blk, 0, stream>>>(
        predb, We1t, be1, (float*)nullptr, Hb, M, 512, 512);
    // ---- GEMM2: EE = Hb @ We2 + be2, fp32 out + bf16 copy (aliases predb) ----
    gemm_mfma<false, true, true><<<dim3(mt, 4), blk, 0, stream>>>(
        Hb, We2t, be2, EE, EEb, M, 512, 512);
    // ---- GEMM3: T1 = relu(EEb @ Wt1 + bt1), fp32 out ----
    gemm_mfma<true, true, false><<<dim3(mt, 1), blk, 0, stream>>>(
        EEb, Wt1t, bt1, T1, (unsigned short*)nullptr, M, 128, 512);

    // ---- head ----
    head_kernel<<<dim3((M + 63) / 64), blk, 0, stream>>>(T1, Wt2, bt2, out, M);
}